// Round 1
// baseline (38.122 us; speedup 1.0000x reference)
//
#include <hip/hip_runtime.h>

constexpr int Bn = 4096;
constexpr int Dn = 128;
constexpr int Cn = 256;
constexpr int ROWS = 8;

// G[d][c] = sum_e (alpha[d][e] + alpha[e][d]) * means[e][c]
// t[c]    = 0.5 * sum_d means[d][c] * G[d][c]   ( = m_c^T alpha m_c exactly )
__global__ __launch_bounds__(128) void setup_kernel(
    const float* __restrict__ means, const float* __restrict__ alpha,
    float* __restrict__ G, float* __restrict__ t) {
    const int c = blockIdx.x;
    const int d = threadIdx.x;  // 0..127
    __shared__ float mcol[Dn];
    __shared__ float red[Dn];
    mcol[d] = means[d * Cn + c];
    __syncthreads();
    float g = 0.f;
    #pragma unroll 4
    for (int e = 0; e < Dn; ++e)
        g = fmaf(alpha[d * Dn + e] + alpha[e * Dn + d], mcol[e], g);
    G[d * Cn + c] = g;
    red[d] = mcol[d] * g;
    __syncthreads();
    #pragma unroll
    for (int off = 64; off > 0; off >>= 1) {
        if (d < off) red[d] += red[d + off];
        __syncthreads();
    }
    if (d == 0) t[c] = 0.5f * red[0];
}

// out[b] = x_b^T alpha x_b + min_c ( t[c] - x_b . G[:,c] )
__global__ __launch_bounds__(256) void main_kernel(
    const float* __restrict__ X, const float* __restrict__ alpha,
    const float* __restrict__ G, const float* __restrict__ t,
    float* __restrict__ out) {
    const int tid = threadIdx.x;
    const int b0 = blockIdx.x * ROWS;
    __shared__ float xs[ROWS][Dn];       // 4 KB
    __shared__ float wred[ROWS][4];
    __shared__ float xaxs[ROWS];

    // stage 8 rows of X (1024 floats), coalesced
    #pragma unroll
    for (int i = 0; i < ROWS * Dn / 256; ++i) {
        int idx = tid + i * 256;
        ((float*)xs)[idx] = X[b0 * Dn + idx];
    }
    __syncthreads();

    const int lane = tid & 63, wv = tid >> 6;

    // ---- xax[r] = x_r^T alpha x_r  (via alpha^T for coalesced reads) ----
    {
        const int d = tid & (Dn - 1);          // column of alpha
        const int e0 = (tid >> 7) * (Dn / 2);  // each half of e-range
        float part[ROWS];
        #pragma unroll
        for (int r = 0; r < ROWS; ++r) part[r] = 0.f;
        for (int e4 = e0; e4 < e0 + Dn / 2; e4 += 4) {
            float a0 = alpha[(e4 + 0) * Dn + d];
            float a1 = alpha[(e4 + 1) * Dn + d];
            float a2 = alpha[(e4 + 2) * Dn + d];
            float a3 = alpha[(e4 + 3) * Dn + d];
            #pragma unroll
            for (int r = 0; r < ROWS; ++r) {
                float4 xv = *(const float4*)&xs[r][e4];   // broadcast b128
                part[r] = fmaf(a0, xv.x, part[r]);
                part[r] = fmaf(a1, xv.y, part[r]);
                part[r] = fmaf(a2, xv.z, part[r]);
                part[r] = fmaf(a3, xv.w, part[r]);
            }
        }
        #pragma unroll
        for (int r = 0; r < ROWS; ++r) {
            float v = part[r] * xs[r][d];
            #pragma unroll
            for (int off = 32; off > 0; off >>= 1)
                v += __shfl_down(v, off);
            if (lane == 0) wred[r][wv] = v;
        }
    }
    __syncthreads();
    if (tid < ROWS)
        xaxs[tid] = wred[tid][0] + wred[tid][1] + wred[tid][2] + wred[tid][3];
    __syncthreads();  // protect wred before reuse

    // ---- cross term + min over c:  thread owns column c = tid ----
    {
        float acc[ROWS];
        #pragma unroll
        for (int r = 0; r < ROWS; ++r) acc[r] = 0.f;
        for (int dd = 0; dd < Dn; dd += 4) {
            float g0 = G[(dd + 0) * Cn + tid];  // coalesced across threads
            float g1 = G[(dd + 1) * Cn + tid];
            float g2 = G[(dd + 2) * Cn + tid];
            float g3 = G[(dd + 3) * Cn + tid];
            #pragma unroll
            for (int r = 0; r < ROWS; ++r) {
                float4 xv = *(const float4*)&xs[r][dd];   // broadcast b128
                acc[r] = fmaf(g0, xv.x, acc[r]);
                acc[r] = fmaf(g1, xv.y, acc[r]);
                acc[r] = fmaf(g2, xv.z, acc[r]);
                acc[r] = fmaf(g3, xv.w, acc[r]);
            }
        }
        float tc = t[tid];
        #pragma unroll
        for (int r = 0; r < ROWS; ++r) {
            float v = tc - acc[r];
            #pragma unroll
            for (int off = 32; off > 0; off >>= 1)
                v = fminf(v, __shfl_down(v, off));
            if (lane == 0) wred[r][wv] = v;
        }
    }
    __syncthreads();
    if (tid < ROWS) {
        float m = fminf(fminf(wred[tid][0], wred[tid][1]),
                        fminf(wred[tid][2], wred[tid][3]));
        out[b0 + tid] = xaxs[tid] + m;
    }
}

extern "C" void kernel_launch(void* const* d_in, const int* in_sizes, int n_in,
                              void* d_out, int out_size, void* d_ws, size_t ws_size,
                              hipStream_t stream) {
    const float* X     = (const float*)d_in[0];
    const float* means = (const float*)d_in[1];
    const float* alpha = (const float*)d_in[2];
    float* out = (float*)d_out;
    float* G = (float*)d_ws;                 // [Dn*Cn]
    float* t = G + Dn * Cn;                  // [Cn]
    setup_kernel<<<Cn, Dn, 0, stream>>>(means, alpha, G, t);
    main_kernel<<<Bn / ROWS, 256, 0, stream>>>(X, alpha, G, t, out);
}

// Round 2
// 17.402 us; speedup vs baseline: 2.1907x; 2.1907x over previous
//
#include <hip/hip_runtime.h>
#include <hip/hip_bf16.h>

constexpr int Bn = 4096;
constexpr int Dn = 128;
constexpr int Cn = 256;
constexpr int Np = Cn + Dn;   // 384 = augmented N' (256 S-cols + 128 H-cols)

typedef __attribute__((ext_vector_type(8))) short bf16x8;  // 8 bf16 = 4 VGPR
typedef __attribute__((ext_vector_type(4))) float f32x4;

static __device__ inline short f2bf(float f) {
    __hip_bfloat16 h = __float2bfloat16(f);
    return *reinterpret_cast<short*>(&h);
}

// blocks [0,Cn):  c = blk.  G[d][c] = sum_e (a[d][e]+a[e][d]) m[e][c]  (fp32)
//   -> Gt[c*Dn + d] = bf16(G),  tvec[c] = 0.5 * sum_d m[d][c]*G[d][c]  (exact m' a m)
// blocks [Cn,Np): dc = blk-Cn. Gt[(Cn+dc)*Dn + e] = bf16(0.5*(a[e][dc]+a[dc][e]))
__global__ __launch_bounds__(128) void setup_kernel(
    const float* __restrict__ means, const float* __restrict__ alpha,
    __hip_bfloat16* __restrict__ Gt, float* __restrict__ tvec) {
    const int tid = threadIdx.x;
    if ((int)blockIdx.x < Cn) {
        const int c = blockIdx.x, d = tid;
        __shared__ float mcol[Dn];
        __shared__ float red[Dn];
        mcol[d] = means[d * Cn + c];
        __syncthreads();
        float g = 0.f;
        #pragma unroll 4
        for (int e = 0; e < Dn; ++e)
            g = fmaf(alpha[d * Dn + e] + alpha[e * Dn + d], mcol[e], g);
        Gt[c * Dn + d] = __float2bfloat16(g);
        red[d] = mcol[d] * g;
        __syncthreads();
        #pragma unroll
        for (int off = 64; off > 0; off >>= 1) {
            if (d < off) red[d] += red[d + off];
            __syncthreads();
        }
        if (d == 0) tvec[c] = 0.5f * red[0];
    } else {
        const int dc = blockIdx.x - Cn, e = tid;
        float v = 0.5f * (alpha[e * Dn + dc] + alpha[dc * Dn + e]);
        Gt[(Cn + dc) * Dn + e] = __float2bfloat16(v);
    }
}

// One block = 16 rows of X, 6 waves. Waves 0-3: S-cols (min epilogue),
// waves 4-5: H-cols (xax epilogue). K=128 -> 4 MFMA steps per tile, 4 tiles/wave.
__global__ __launch_bounds__(384) void main_kernel(
    const float* __restrict__ X, const __hip_bfloat16* __restrict__ Gt,
    const float* __restrict__ tvec, float* __restrict__ out) {
    const int tid = threadIdx.x;
    const int w = tid >> 6;          // wave 0..5
    const int lane = tid & 63;
    const int l15 = lane & 15;
    const int lh = lane >> 4;        // 0..3
    const int b0 = blockIdx.x * 16;

    __shared__ float smin[4][16];
    __shared__ float sxax[2][16];

    // ---- A fragments (shared geometry across waves): A[row=l15][k=32k0+8lh+i]
    bf16x8 af[4];
    const float* xrow = X + (b0 + l15) * Dn;
    #pragma unroll
    for (int k0 = 0; k0 < 4; ++k0) {
        const float4* p = (const float4*)(xrow + 32 * k0 + 8 * lh);
        float4 x0 = p[0], x1 = p[1];
        bf16x8 a;
        a[0] = f2bf(x0.x); a[1] = f2bf(x0.y); a[2] = f2bf(x0.z); a[3] = f2bf(x0.w);
        a[4] = f2bf(x1.x); a[5] = f2bf(x1.y); a[6] = f2bf(x1.z); a[7] = f2bf(x1.w);
        af[k0] = a;
    }

    // ---- B fragments: B[k=32k0+8lh+i][col] = Gt[col*Dn + k]  (col-major storage)
    bf16x8 bfr[4][4];
    #pragma unroll
    for (int tt = 0; tt < 4; ++tt) {
        const int col = 64 * w + 16 * tt + l15;
        const __hip_bfloat16* gcol = Gt + col * Dn;
        #pragma unroll
        for (int k0 = 0; k0 < 4; ++k0)
            bfr[tt][k0] = *(const bf16x8*)(gcol + 32 * k0 + 8 * lh);
    }

    f32x4 acc[4];
    #pragma unroll
    for (int tt = 0; tt < 4; ++tt) acc[tt] = (f32x4){0.f, 0.f, 0.f, 0.f};

    #pragma unroll
    for (int k0 = 0; k0 < 4; ++k0)
        #pragma unroll
        for (int tt = 0; tt < 4; ++tt)
            acc[tt] = __builtin_amdgcn_mfma_f32_16x16x32_bf16(
                af[k0], bfr[tt][k0], acc[tt], 0, 0, 0);

    // C layout (verified): col = lane&15, row = 4*(lane>>4) + reg
    if (w < 4) {
        // min over this wave's 64 S-columns of (t[c] - S[b,c])
        float mr[4];
        #pragma unroll
        for (int r = 0; r < 4; ++r) mr[r] = 1e30f;
        #pragma unroll
        for (int tt = 0; tt < 4; ++tt) {
            float tc = tvec[64 * w + 16 * tt + l15];
            #pragma unroll
            for (int r = 0; r < 4; ++r) mr[r] = fminf(mr[r], tc - acc[tt][r]);
        }
        #pragma unroll
        for (int r = 0; r < 4; ++r)
            #pragma unroll
            for (int m = 1; m < 16; m <<= 1)
                mr[r] = fminf(mr[r], __shfl_xor(mr[r], m));
        if (l15 == 0)
            #pragma unroll
            for (int r = 0; r < 4; ++r) smin[w][4 * lh + r] = mr[r];
    } else {
        // xax partial: sum_d X[row,d] * H[row,d] over this wave's 64 d-columns
        float p[4] = {0.f, 0.f, 0.f, 0.f};
        #pragma unroll
        for (int tt = 0; tt < 4; ++tt) {
            const int d = 64 * (w - 4) + 16 * tt + l15;
            #pragma unroll
            for (int r = 0; r < 4; ++r) {
                const int row = 4 * lh + r;
                p[r] = fmaf(acc[tt][r], X[(b0 + row) * Dn + d], p[r]);
            }
        }
        #pragma unroll
        for (int r = 0; r < 4; ++r)
            #pragma unroll
            for (int m = 1; m < 16; m <<= 1)
                p[r] += __shfl_xor(p[r], m);
        if (l15 == 0)
            #pragma unroll
            for (int r = 0; r < 4; ++r) sxax[w - 4][4 * lh + r] = p[r];
    }
    __syncthreads();

    if (tid < 16) {
        float mn = fminf(fminf(smin[0][tid], smin[1][tid]),
                         fminf(smin[2][tid], smin[3][tid]));
        out[b0 + tid] = sxax[0][tid] + sxax[1][tid] + mn;
    }
}

extern "C" void kernel_launch(void* const* d_in, const int* in_sizes, int n_in,
                              void* d_out, int out_size, void* d_ws, size_t ws_size,
                              hipStream_t stream) {
    const float* X     = (const float*)d_in[0];
    const float* means = (const float*)d_in[1];
    const float* alpha = (const float*)d_in[2];
    float* out = (float*)d_out;
    __hip_bfloat16* Gt = (__hip_bfloat16*)d_ws;                       // [Np*Dn]
    float* tvec = (float*)((char*)d_ws + Np * Dn * sizeof(__hip_bfloat16)); // [Cn]

    setup_kernel<<<Np, 128, 0, stream>>>(means, alpha, Gt, tvec);
    main_kernel<<<Bn / 16, 384, 0, stream>>>(X, Gt, tvec, out);
}